// Round 1
// baseline (2141.430 us; speedup 1.0000x reference)
//
#include <hip/hip_runtime.h>

#define DEVI __device__ __forceinline__

typedef unsigned int u32;
typedef unsigned short u16;

constexpr int Bc = 2, Sc = 2048, HIDc = 2048, Hc = 16, Dc = 128;
constexpr int Mrows = Bc * Sc;                 // 4096
constexpr float SCALE = 0.08838834764831845f;  // 1/sqrt(128)

typedef float f32x4 __attribute__((ext_vector_type(4)));
typedef __bf16 bf16x8 __attribute__((ext_vector_type(8)));

DEVI float bf2f(u16 v) { return __builtin_bit_cast(float, (u32)v << 16); }
DEVI float blo(u32 u) { return __builtin_bit_cast(float, u << 16); }
DEVI float bhi(u32 u) { return __builtin_bit_cast(float, u & 0xffff0000u); }
DEVI u16 f2bf(float x) {
  u32 u = __builtin_bit_cast(u32, x);
  u32 r = (u + 0x7fffu + ((u >> 16) & 1u)) >> 16;
  return (u16)r;
}

DEVI void async16(void* lds, const void* g) {
  __builtin_amdgcn_global_load_lds((const __attribute__((address_space(1))) void*)g,
                                   (__attribute__((address_space(3))) void*)lds,
                                   16, 0, 0);
}

// ---------------- dtype detect: flag=1 if inputs are bf16-packed ----------------
__global__ void detect_dtype(const u32* __restrict__ hs, int* __restrict__ flag) {
  __shared__ int cnt;
  if (threadIdx.x == 0) cnt = 0;
  __syncthreads();
  int ok = 0;
  for (int i = threadIdx.x; i < 512; i += 256) {
    u32 lo = hs[i] & 0xffffu;
    u32 e = (lo >> 7) & 0xffu;
    if (lo == 0u || (e >= 118u && e <= 134u)) ok++;
  }
  atomicAdd(&cnt, ok);
  __syncthreads();
  if (threadIdx.x == 0) *flag = (cnt > 256) ? 1 : 0;
}

// ---------------- hidden_states -> bf16 canonical buffer ----------------
__global__ __launch_bounds__(256) void ingest_hs(const void* __restrict__ in, u16* __restrict__ out,
                                                 const int* __restrict__ flag, int n) {
  int i = (blockIdx.x * 256 + threadIdx.x) * 8;
  if (i >= n) return;
  if (*flag) {
    *(uint4*)&out[i] = *(const uint4*)&((const u16*)in)[i];
  } else {
    const float* f = (const float*)in;
    u16 tmp[8];
#pragma unroll
    for (int j = 0; j < 8; ++j) tmp[j] = f2bf(f[i + j]);
    *(uint4*)&out[i] = *(const uint4*)tmp;
  }
}

// ---------------- weight transpose (R x C) -> bf16 (C x R) ----------------
__global__ __launch_bounds__(256) void transpose_w(const void* __restrict__ in, u16* __restrict__ out,
                                                   int R, int C, const int* __restrict__ flag) {
  __shared__ u16 tile[32][33];
  const bool bf = (*flag != 0);
  int c0 = blockIdx.x * 32, r0 = blockIdx.y * 32;
  int tx = threadIdx.x & 31, ty = threadIdx.x >> 5;  // ty 0..7
#pragma unroll
  for (int i = 0; i < 32; i += 8) {
    size_t idx = (size_t)(r0 + ty + i) * C + (c0 + tx);
    tile[ty + i][tx] = bf ? ((const u16*)in)[idx] : f2bf(((const float*)in)[idx]);
  }
  __syncthreads();
#pragma unroll
  for (int i = 0; i < 32; i += 8)
    out[(size_t)(c0 + ty + i) * R + (r0 + tx)] = tile[tx][ty + i];
}

// ---------------- biases -> bf16 (bq @0, bkv @2048, bp @2304) ----------------
__global__ __launch_bounds__(256) void cvt_bias(const void* __restrict__ bq, const void* __restrict__ bkv,
                                                const void* __restrict__ bp, u16* __restrict__ out,
                                                const int* __restrict__ flag) {
  int i = blockIdx.x * 256 + threadIdx.x;
  if (i >= 4352) return;
  const bool bf = (*flag != 0);
  const void* src;
  int j;
  if (i < 2048) { src = bq; j = i; }
  else if (i < 2304) { src = bkv; j = i - 2048; }
  else { src = bp; j = i - 2304; }
  out[i] = bf ? ((const u16*)src)[j] : f2bf(((const float*)src)[j]);
}

// ---------------- bf16 GEMM: C[M,N] = A[M,K] * BT[N,K]^T + bias ----------------
__global__ __launch_bounds__(256) void gemm_bt(const u16* __restrict__ A,
                                               const u16* __restrict__ BT,
                                               const u16* __restrict__ bias,
                                               void* __restrict__ C,
                                               int M, int N, int K,
                                               const int* __restrict__ flag,
                                               int is_final) {
  __shared__ __align__(16) u16 As[128 * 32];
  __shared__ __align__(16) u16 Bs[128 * 32];
  const int tid = threadIdx.x;
  const int bn = blockIdx.x, bm = blockIdx.y;
  const int wave = tid >> 6, lane = tid & 63;
  const int wm = (wave >> 1) * 64, wn = (wave & 1) * 64;
  const int lr = lane & 15, kq = lane >> 4;
  f32x4 acc[4][4] = {};
  const size_t a_base = (size_t)bm * 128 * K;
  const size_t b_base = (size_t)bn * 128 * K;
  for (int k0 = 0; k0 < K; k0 += 32) {
#pragma unroll
    for (int it = 0; it < 2; ++it) {
      int off = it * 4096 + tid * 16;  // byte offset within 8KB tile
      int row = off >> 6;              // 64 bytes per row (32 bf16)
      int col = (off & 63) >> 1;       // element col within BK
      async16(&As[off >> 1], A + a_base + (size_t)row * K + k0 + col);
      async16(&Bs[off >> 1], BT + b_base + (size_t)row * K + k0 + col);
    }
    __syncthreads();
    bf16x8 af[4], bfr[4];
#pragma unroll
    for (int i = 0; i < 4; ++i) {
      af[i]  = *(const bf16x8*)&As[(wm + i * 16 + lr) * 32 + kq * 8];
      bfr[i] = *(const bf16x8*)&Bs[(wn + i * 16 + lr) * 32 + kq * 8];
    }
#pragma unroll
    for (int mi = 0; mi < 4; ++mi)
#pragma unroll
      for (int ni = 0; ni < 4; ++ni)
        acc[mi][ni] = __builtin_amdgcn_mfma_f32_16x16x32_bf16(af[mi], bfr[ni], acc[mi][ni], 0, 0, 0);
    __syncthreads();
  }
  const bool out16 = (!is_final) || (*flag != 0);
#pragma unroll
  for (int mi = 0; mi < 4; ++mi)
#pragma unroll
    for (int ni = 0; ni < 4; ++ni) {
      int col = bn * 128 + wn + ni * 16 + lr;
      float bv = bf2f(bias[col]);
#pragma unroll
      for (int rr = 0; rr < 4; ++rr) {
        int row = bm * 128 + wm + mi * 16 + kq * 4 + rr;
        float v = acc[mi][ni][rr] + bv;
        size_t idx = (size_t)row * N + col;
        if (out16) ((u16*)C)[idx] = f2bf(v);
        else ((float*)C)[idx] = v;
      }
    }
}

// ---------------- causal MQA flash attention (VALU baseline) ----------------
// Q: (B*S, H*D) bf16, KV: (B*S, 256) bf16 (K | V), O: (B*S, H*D) bf16
__global__ __launch_bounds__(256) void flash_kernel(const u16* __restrict__ Q,
                                                    const u16* __restrict__ KV,
                                                    u16* __restrict__ O) {
  __shared__ __align__(16) u16 L[64 * 256];  // 64 keys x (128 K | 128 V) = 32 KB
  const int qt = blockIdx.x, h = blockIdx.y, b = blockIdx.z;
  const int tid = threadIdx.x;
  const int r = tid >> 2, p = tid & 3;  // row 0..63, dim-part 0..3
  const int s = qt * 64 + r;
  const u16* qptr = Q + (size_t)(b * Sc + s) * (Hc * Dc) + h * Dc + p * 32;
  float qf[32], acc[32];
  {
    const uint4* qp = (const uint4*)qptr;
#pragma unroll
    for (int c = 0; c < 4; ++c) {
      uint4 w = qp[c];
      qf[c * 8 + 0] = blo(w.x) * SCALE; qf[c * 8 + 1] = bhi(w.x) * SCALE;
      qf[c * 8 + 2] = blo(w.y) * SCALE; qf[c * 8 + 3] = bhi(w.y) * SCALE;
      qf[c * 8 + 4] = blo(w.z) * SCALE; qf[c * 8 + 5] = bhi(w.z) * SCALE;
      qf[c * 8 + 6] = blo(w.w) * SCALE; qf[c * 8 + 7] = bhi(w.w) * SCALE;
    }
  }
#pragma unroll
  for (int i = 0; i < 32; ++i) acc[i] = 0.f;
  float m = -1e30f, l = 0.f;
  const int kmax = (qt + 1) * 64;
  for (int k0 = 0; k0 < kmax; k0 += 64) {
    const u16* src = KV + (size_t)(b * Sc + k0) * 256;
#pragma unroll
    for (int i = 0; i < 8; ++i) {
      int off = i * 2048 + tid * 8;
      *(uint4*)&L[off] = *(const uint4*)&src[off];
    }
    __syncthreads();
    for (int j = 0; j < 64; ++j) {
      int t = k0 + j;
      if (t > s) break;  // causal; all 4 lanes of a row exit together
      const uint4* kr = (const uint4*)&L[j * 256 + p * 32];
      float sp = 0.f;
#pragma unroll
      for (int c = 0; c < 4; ++c) {
        uint4 w = kr[c];
        sp += qf[c * 8 + 0] * blo(w.x) + qf[c * 8 + 1] * bhi(w.x)
            + qf[c * 8 + 2] * blo(w.y) + qf[c * 8 + 3] * bhi(w.y)
            + qf[c * 8 + 4] * blo(w.z) + qf[c * 8 + 5] * bhi(w.z)
            + qf[c * 8 + 6] * blo(w.w) + qf[c * 8 + 7] * bhi(w.w);
      }
      sp += __shfl_xor(sp, 1);
      sp += __shfl_xor(sp, 2);
      if (sp > m) {  // lazy rescale; rare after warm-up
        float corr = __expf(m - sp);
#pragma unroll
        for (int i = 0; i < 32; ++i) acc[i] *= corr;
        l *= corr;
        m = sp;
      }
      float e = __expf(sp - m);
      l += e;
      const uint4* vr = (const uint4*)&L[j * 256 + 128 + p * 32];
#pragma unroll
      for (int c = 0; c < 4; ++c) {
        uint4 w = vr[c];
        acc[c * 8 + 0] += e * blo(w.x); acc[c * 8 + 1] += e * bhi(w.x);
        acc[c * 8 + 2] += e * blo(w.y); acc[c * 8 + 3] += e * bhi(w.y);
        acc[c * 8 + 4] += e * blo(w.z); acc[c * 8 + 5] += e * bhi(w.z);
        acc[c * 8 + 6] += e * blo(w.w); acc[c * 8 + 7] += e * bhi(w.w);
      }
    }
    __syncthreads();
  }
  float inv = 1.f / l;
  u16* optr = O + (size_t)(b * Sc + s) * (Hc * Dc) + h * Dc + p * 32;
#pragma unroll
  for (int c = 0; c < 4; ++c) {
    u16 tmp[8];
#pragma unroll
    for (int i = 0; i < 8; ++i) tmp[i] = f2bf(acc[c * 8 + i] * inv);
    *(uint4*)&optr[c * 8] = *(const uint4*)tmp;
  }
}

extern "C" void kernel_launch(void* const* d_in, const int* in_sizes, int n_in,
                              void* d_out, int out_size, void* d_ws, size_t ws_size,
                              hipStream_t stream) {
  (void)in_sizes; (void)n_in; (void)out_size; (void)ws_size;
  const void* hs  = d_in[0];
  // d_in[1] = attention_mask: exactly causal by construction -> applied analytically
  const void* Wq  = d_in[2];
  const void* bq  = d_in[3];
  const void* Wkv = d_in[4];
  const void* bkv = d_in[5];
  const void* Wp  = d_in[6];
  const void* bp  = d_in[7];

  char* ws = (char*)d_ws;
  int* flag  = (int*)(ws + 0);
  u16* HSb   = (u16*)(ws + 256);        // 4096x2048 bf16
  u16* WqT   = (u16*)(ws + 16777472);   // 2048x2048
  u16* WkvT  = (u16*)(ws + 25166080);   // 256x2048
  u16* WpT   = (u16*)(ws + 26214656);   // 2048x2048
  u16* biasB = (u16*)(ws + 34603264);   // 4352
  u16* Qb    = (u16*)(ws + 34611968);   // 4096x2048
  u16* KVb   = (u16*)(ws + 51389184);   // 4096x256
  u16* ATTNb = (u16*)(ws + 53486336);   // 4096x2048

  detect_dtype<<<1, 256, 0, stream>>>((const u32*)hs, flag);
  ingest_hs<<<4096, 256, 0, stream>>>(hs, HSb, flag, Mrows * HIDc);
  transpose_w<<<dim3(64, 64), 256, 0, stream>>>(Wq, WqT, 2048, 2048, flag);
  transpose_w<<<dim3(8, 64), 256, 0, stream>>>(Wkv, WkvT, 2048, 256, flag);
  transpose_w<<<dim3(64, 64), 256, 0, stream>>>(Wp, WpT, 2048, 2048, flag);
  cvt_bias<<<17, 256, 0, stream>>>(bq, bkv, bp, biasB, flag);

  // q = hs @ Wq + bq   (4096 x 2048 x 2048)
  gemm_bt<<<dim3(16, 32), 256, 0, stream>>>(HSb, WqT, biasB, Qb, 4096, 2048, 2048, flag, 0);
  // kv = hs @ Wkv + bkv (4096 x 256 x 2048)
  gemm_bt<<<dim3(2, 32), 256, 0, stream>>>(HSb, WkvT, biasB + 2048, KVb, 4096, 256, 2048, flag, 0);
  // causal MQA attention
  flash_kernel<<<dim3(32, 16, 2), 256, 0, stream>>>(Qb, KVb, ATTNb);
  // out = attn @ Wp + bp (4096 x 2048 x 2048), dtype per detected flag
  gemm_bt<<<dim3(16, 32), 256, 0, stream>>>(ATTNb, WpT, biasB + 2304, d_out, 4096, 2048, 2048, flag, 1);
}

// Round 2
// 453.387 us; speedup vs baseline: 4.7232x; 4.7232x over previous
//
#include <hip/hip_runtime.h>

#define DEVI __device__ __forceinline__

typedef unsigned int u32;
typedef unsigned short u16;

constexpr int Bc = 2, Sc = 2048, HIDc = 2048, Hc = 16, Dc = 128;
constexpr int Mrows = Bc * Sc;                 // 4096
constexpr float SCALE = 0.08838834764831845f;  // 1/sqrt(128)

typedef float f32x4 __attribute__((ext_vector_type(4)));
typedef __bf16 bf16x8 __attribute__((ext_vector_type(8)));

DEVI float bf2f(u16 v) { return __builtin_bit_cast(float, (u32)v << 16); }
DEVI float blo(u32 u) { return __builtin_bit_cast(float, u << 16); }
DEVI float bhi(u32 u) { return __builtin_bit_cast(float, u & 0xffff0000u); }
DEVI u16 f2bf(float x) {
  u32 u = __builtin_bit_cast(u32, x);
  u32 r = (u + 0x7fffu + ((u >> 16) & 1u)) >> 16;
  return (u16)r;
}

DEVI void async16(void* lds, const void* g) {
  __builtin_amdgcn_global_load_lds((const __attribute__((address_space(1))) void*)g,
                                   (__attribute__((address_space(3))) void*)lds,
                                   16, 0, 0);
}

// ---------------- dtype detect: flag=1 if inputs are bf16-packed ----------------
__global__ void detect_dtype(const u32* __restrict__ hs, int* __restrict__ flag) {
  __shared__ int cnt;
  if (threadIdx.x == 0) cnt = 0;
  __syncthreads();
  int ok = 0;
  for (int i = threadIdx.x; i < 512; i += 256) {
    u32 lo = hs[i] & 0xffffu;
    u32 e = (lo >> 7) & 0xffu;
    if (lo == 0u || (e >= 118u && e <= 134u)) ok++;
  }
  atomicAdd(&cnt, ok);
  __syncthreads();
  if (threadIdx.x == 0) *flag = (cnt > 256) ? 1 : 0;
}

// ---------------- hidden_states -> bf16 canonical buffer ----------------
__global__ __launch_bounds__(256) void ingest_hs(const void* __restrict__ in, u16* __restrict__ out,
                                                 const int* __restrict__ flag, int n) {
  int i = (blockIdx.x * 256 + threadIdx.x) * 8;
  if (i >= n) return;
  if (*flag) {
    *(uint4*)&out[i] = *(const uint4*)&((const u16*)in)[i];
  } else {
    const float* f = (const float*)in;
    u16 tmp[8];
#pragma unroll
    for (int j = 0; j < 8; ++j) tmp[j] = f2bf(f[i + j]);
    *(uint4*)&out[i] = *(const uint4*)tmp;
  }
}

// ---------------- weight transpose (R x C) -> bf16 (C x R) ----------------
__global__ __launch_bounds__(256) void transpose_w(const void* __restrict__ in, u16* __restrict__ out,
                                                   int R, int C, const int* __restrict__ flag) {
  __shared__ u16 tile[32][33];
  const bool bf = (*flag != 0);
  int c0 = blockIdx.x * 32, r0 = blockIdx.y * 32;
  int tx = threadIdx.x & 31, ty = threadIdx.x >> 5;  // ty 0..7
#pragma unroll
  for (int i = 0; i < 32; i += 8) {
    size_t idx = (size_t)(r0 + ty + i) * C + (c0 + tx);
    tile[ty + i][tx] = bf ? ((const u16*)in)[idx] : f2bf(((const float*)in)[idx]);
  }
  __syncthreads();
#pragma unroll
  for (int i = 0; i < 32; i += 8)
    out[(size_t)(c0 + ty + i) * R + (r0 + tx)] = tile[tx][ty + i];
}

// ---------------- biases -> bf16 (bq @0, bkv @2048, bp @2304) ----------------
__global__ __launch_bounds__(256) void cvt_bias(const void* __restrict__ bq, const void* __restrict__ bkv,
                                                const void* __restrict__ bp, u16* __restrict__ out,
                                                const int* __restrict__ flag) {
  int i = blockIdx.x * 256 + threadIdx.x;
  if (i >= 4352) return;
  const bool bf = (*flag != 0);
  const void* src;
  int j;
  if (i < 2048) { src = bq; j = i; }
  else if (i < 2304) { src = bkv; j = i - 2048; }
  else { src = bp; j = i - 2304; }
  out[i] = bf ? ((const u16*)src)[j] : f2bf(((const float*)src)[j]);
}

// ---------------- bf16 GEMM: C[M,N] = A[M,K] * BT[N,K]^T + bias ----------------
// mode 0: bf16 out (row-major). mode 1: final output, dtype per *flag.
// mode 2: KV writer — K part (col<128) -> KsG chunk-swizzled, V part -> VtG
//         transposed + chunk-swizzled, both ready for async16 staging.
__global__ __launch_bounds__(256) void gemm_bt(const u16* __restrict__ A,
                                               const u16* __restrict__ BT,
                                               const u16* __restrict__ bias,
                                               void* __restrict__ C,
                                               int M, int N, int K,
                                               const int* __restrict__ flag,
                                               int mode) {
  __shared__ __align__(16) u16 As[128 * 32];
  __shared__ __align__(16) u16 Bs[128 * 32];
  const int tid = threadIdx.x;
  const int bn = blockIdx.x, bm = blockIdx.y;
  const int wave = tid >> 6, lane = tid & 63;
  const int wm = (wave >> 1) * 64, wn = (wave & 1) * 64;
  const int lr = lane & 15, kq = lane >> 4;
  f32x4 acc[4][4] = {};
  const size_t a_base = (size_t)bm * 128 * K;
  const size_t b_base = (size_t)bn * 128 * K;
  for (int k0 = 0; k0 < K; k0 += 32) {
#pragma unroll
    for (int it = 0; it < 2; ++it) {
      int off = it * 4096 + tid * 16;  // byte offset within 8KB tile
      int row = off >> 6;              // 64 bytes per row (32 bf16)
      int col = (off & 63) >> 1;       // element col within BK
      async16(&As[off >> 1], A + a_base + (size_t)row * K + k0 + col);
      async16(&Bs[off >> 1], BT + b_base + (size_t)row * K + k0 + col);
    }
    __syncthreads();
    bf16x8 af[4], bfr[4];
#pragma unroll
    for (int i = 0; i < 4; ++i) {
      af[i]  = *(const bf16x8*)&As[(wm + i * 16 + lr) * 32 + kq * 8];
      bfr[i] = *(const bf16x8*)&Bs[(wn + i * 16 + lr) * 32 + kq * 8];
    }
#pragma unroll
    for (int mi = 0; mi < 4; ++mi)
#pragma unroll
      for (int ni = 0; ni < 4; ++ni)
        acc[mi][ni] = __builtin_amdgcn_mfma_f32_16x16x32_bf16(af[mi], bfr[ni], acc[mi][ni], 0, 0, 0);
    __syncthreads();
  }
  if (mode == 2) {
    u16* KsG = (u16*)C;
    u16* VtG = KsG + (size_t)4096 * 128;
#pragma unroll
    for (int mi = 0; mi < 4; ++mi)
#pragma unroll
      for (int ni = 0; ni < 4; ++ni) {
        int col = bn * 128 + wn + ni * 16 + lr;
        float bv = bf2f(bias[col]);
#pragma unroll
        for (int rr = 0; rr < 4; ++rr) {
          int row = bm * 128 + wm + mi * 16 + kq * 4 + rr;
          u16 v = f2bf(acc[mi][ni][rr] + bv);
          if (col < 128) {
            int d = col;
            KsG[(size_t)row * 128 + (((d >> 3) ^ (row & 15)) << 3) + (d & 7)] = v;
          } else {
            int d = col - 128, bb = row >> 11, s = row & 2047;
            VtG[((size_t)(bb * 128 + d)) * 2048 + (s & ~63) +
                ((((s >> 3) & 7) ^ (d & 7)) << 3) + (s & 7)] = v;
          }
        }
      }
    return;
  }
  const bool out16 = (mode == 0) || (*flag != 0);
#pragma unroll
  for (int mi = 0; mi < 4; ++mi)
#pragma unroll
    for (int ni = 0; ni < 4; ++ni) {
      int col = bn * 128 + wn + ni * 16 + lr;
      float bv = bf2f(bias[col]);
#pragma unroll
      for (int rr = 0; rr < 4; ++rr) {
        int row = bm * 128 + wm + mi * 16 + kq * 4 + rr;
        float v = acc[mi][ni][rr] + bv;
        size_t idx = (size_t)row * N + col;
        if (out16) ((u16*)C)[idx] = f2bf(v);
        else ((float*)C)[idx] = v;
      }
    }
}

// ---------------- causal MQA flash attention, MFMA version ----------------
// Q: (B*S, H*D) bf16. KsG: (B*S, 128) chunk-swizzled. VtG: (B, 128, S)
// chunk-swizzled per 64-key tile. O: (B*S, H*D) bf16.
// Block = (q-pair, h, b); pairs q-tiles (i, 31-i) for constant causal work.
constexpr int PS_STRIDE = 72;

__global__ __launch_bounds__(256) void flash_mfma(const u16* __restrict__ Q,
                                                  const u16* __restrict__ KsG,
                                                  const u16* __restrict__ VtG,
                                                  u16* __restrict__ O) {
  __shared__ __align__(16) u16 Ks[64 * 128];        // 16 KB, swizzled
  __shared__ __align__(16) u16 Vt[128 * 64];        // 16 KB, swizzled
  __shared__ __align__(16) u16 Ps[64 * PS_STRIDE];  // 9 KB, padded
  const int pairidx = blockIdx.x, h = blockIdx.y, b = blockIdx.z;
  const int tid = threadIdx.x;
  const int wave = tid >> 6, lane = tid & 63;
  const int lr = lane & 15, kq = lane >> 4;

  for (int half = 0; half < 2; ++half) {
    const int qt = (half == 0) ? pairidx : 31 - pairidx;
    // Q fragments for this wave's 16 rows, held for the whole tile
    bf16x8 qf[4];
    const u16* qbase = Q + ((size_t)(b * 2048 + qt * 64 + wave * 16 + lr)) * 2048 + h * 128;
#pragma unroll
    for (int kk = 0; kk < 4; ++kk)
      qf[kk] = *(const bf16x8*)(qbase + kk * 32 + kq * 8);
    f32x4 of[8] = {};
    float mrow[4], lrow[4];
#pragma unroll
    for (int r = 0; r < 4; ++r) { mrow[r] = -1e30f; lrow[r] = 0.f; }
    const int srow = qt * 64 + wave * 16 + kq * 4;  // + r for reg r

    for (int k0 = 0; k0 <= qt * 64; k0 += 64) {
      __syncthreads();  // previous step's LDS reads done before overwrite
      {  // stage K tile (16 KB), pre-swizzled global -> sequential async16
        const u16* g = KsG + ((size_t)(b * 2048 + k0)) * 128;
#pragma unroll
        for (int it = 0; it < 4; ++it)
          async16(&Ks[it * 2048 + tid * 8], g + it * 2048 + tid * 8);
      }
      {  // stage V^T tile (16 KB): 1024 chunks of 8 bf16
        const size_t vbase = ((size_t)b * 128) * 2048 + k0;
#pragma unroll
        for (int it = 0; it < 4; ++it) {
          int chunk = it * 256 + tid;
          async16(&Vt[chunk * 8], VtG + vbase + (size_t)(chunk >> 3) * 2048 + (chunk & 7) * 8);
        }
      }
      __syncthreads();  // drains vmcnt for async16

      const bool diag = (k0 == qt * 64);
      // ---- S = Q K^T  (16 mfma) ----
      f32x4 sf[4] = {};
#pragma unroll
      for (int nt = 0; nt < 4; ++nt) {
        int keyl = nt * 16 + lr;
#pragma unroll
        for (int kk = 0; kk < 4; ++kk) {
          const bf16x8 kf = *(const bf16x8*)&Ks[keyl * 128 + ((((kk << 2) + kq) ^ lr) << 3)];
          sf[nt] = __builtin_amdgcn_mfma_f32_16x16x32_bf16(qf[kk], kf, sf[nt], 0, 0, 0);
        }
      }
      // ---- scale + causal mask ----
      float sv[4][4];
#pragma unroll
      for (int nt = 0; nt < 4; ++nt) {
        int t = k0 + nt * 16 + lr;
#pragma unroll
        for (int r = 0; r < 4; ++r) {
          float v = sf[nt][r] * SCALE;
          if (diag && t > srow + r) v = -1e30f;
          sv[nt][r] = v;
        }
      }
      // ---- online softmax (rows live across 16 lanes of a quad) ----
#pragma unroll
      for (int r = 0; r < 4; ++r) {
        float mx = fmaxf(fmaxf(sv[0][r], sv[1][r]), fmaxf(sv[2][r], sv[3][r]));
        mx = fmaxf(mx, __shfl_xor(mx, 1));
        mx = fmaxf(mx, __shfl_xor(mx, 2));
        mx = fmaxf(mx, __shfl_xor(mx, 4));
        mx = fmaxf(mx, __shfl_xor(mx, 8));
        float mnew = fmaxf(mrow[r], mx);
        float corr = __expf(mrow[r] - mnew);
        mrow[r] = mnew;
        lrow[r] *= corr;
#pragma unroll
        for (int dt = 0; dt < 8; ++dt) of[dt][r] *= corr;
        float rs = 0.f;
#pragma unroll
        for (int nt = 0; nt < 4; ++nt) {
          float p = __expf(sv[nt][r] - mnew);
          sv[nt][r] = p;
          rs += p;
        }
        rs += __shfl_xor(rs, 1);
        rs += __shfl_xor(rs, 2);
        rs += __shfl_xor(rs, 4);
        rs += __shfl_xor(rs, 8);
        lrow[r] += rs;
      }
      // ---- P: C-layout regs -> LDS (A-layout relayout) ----
#pragma unroll
      for (int nt = 0; nt < 4; ++nt)
#pragma unroll
        for (int r = 0; r < 4; ++r)
          Ps[(wave * 16 + kq * 4 + r) * PS_STRIDE + nt * 16 + lr] = f2bf(sv[nt][r]);
      // same-wave LDS RAW: DS ops execute in order per wave; compiler inserts lgkmcnt
      // ---- O += P V  (16 mfma) ----
#pragma unroll
      for (int ks = 0; ks < 2; ++ks) {
        const bf16x8 pf = *(const bf16x8*)&Ps[(wave * 16 + lr) * PS_STRIDE + ks * 32 + kq * 8];
#pragma unroll
        for (int dt = 0; dt < 8; ++dt) {
          int d = dt * 16 + lr;
          const bf16x8 vf = *(const bf16x8*)&Vt[d * 64 + ((((ks << 2) + kq) ^ (d & 7)) << 3)];
          of[dt] = __builtin_amdgcn_mfma_f32_16x16x32_bf16(pf, vf, of[dt], 0, 0, 0);
        }
      }
    }
    // ---- epilogue: normalize + store ----
#pragma unroll
    for (int r = 0; r < 4; ++r) lrow[r] = 1.f / lrow[r];
    u16* obase = O + ((size_t)(b * 2048 + qt * 64 + wave * 16 + kq * 4)) * 2048 + h * 128;
#pragma unroll
    for (int dt = 0; dt < 8; ++dt)
#pragma unroll
      for (int r = 0; r < 4; ++r)
        obase[(size_t)r * 2048 + dt * 16 + lr] = f2bf(of[dt][r] * lrow[r]);
    __syncthreads();  // all waves done with LDS before next half restages
  }
}

extern "C" void kernel_launch(void* const* d_in, const int* in_sizes, int n_in,
                              void* d_out, int out_size, void* d_ws, size_t ws_size,
                              hipStream_t stream) {
  (void)in_sizes; (void)n_in; (void)out_size; (void)ws_size;
  const void* hs  = d_in[0];
  // d_in[1] = attention_mask: exactly causal by construction -> applied analytically
  const void* Wq  = d_in[2];
  const void* bq  = d_in[3];
  const void* Wkv = d_in[4];
  const void* bkv = d_in[5];
  const void* Wp  = d_in[6];
  const void* bp  = d_in[7];

  char* ws = (char*)d_ws;
  int* flag  = (int*)(ws + 0);
  u16* HSb   = (u16*)(ws + 256);        // 4096x2048 bf16
  u16* WqT   = (u16*)(ws + 16777472);   // 2048x2048
  u16* WkvT  = (u16*)(ws + 25166080);   // 256x2048
  u16* WpT   = (u16*)(ws + 26214656);   // 2048x2048
  u16* biasB = (u16*)(ws + 34603264);   // 4352
  u16* Qb    = (u16*)(ws + 34611968);   // 4096x2048
  u16* KsG   = (u16*)(ws + 51389184);   // 4096x128 swizzled K
  u16* VtG   = (u16*)(ws + 52437760);   // 2x128x2048 swizzled V^T
  u16* ATTNb = (u16*)(ws + 53486336);   // 4096x2048

  detect_dtype<<<1, 256, 0, stream>>>((const u32*)hs, flag);
  ingest_hs<<<4096, 256, 0, stream>>>(hs, HSb, flag, Mrows * HIDc);
  transpose_w<<<dim3(64, 64), 256, 0, stream>>>(Wq, WqT, 2048, 2048, flag);
  transpose_w<<<dim3(8, 64), 256, 0, stream>>>(Wkv, WkvT, 2048, 256, flag);
  transpose_w<<<dim3(64, 64), 256, 0, stream>>>(Wp, WpT, 2048, 2048, flag);
  cvt_bias<<<17, 256, 0, stream>>>(bq, bkv, bp, biasB, flag);

  // q = hs @ Wq + bq   (4096 x 2048 x 2048)
  gemm_bt<<<dim3(16, 32), 256, 0, stream>>>(HSb, WqT, biasB, Qb, 4096, 2048, 2048, flag, 0);
  // kv = hs @ Wkv + bkv (4096 x 256 x 2048) -> swizzled KsG / VtG
  gemm_bt<<<dim3(2, 32), 256, 0, stream>>>(HSb, WkvT, biasB + 2048, KsG, 4096, 256, 2048, flag, 2);
  // causal MQA attention (MFMA flash)
  flash_mfma<<<dim3(16, 16, 2), 256, 0, stream>>>(Qb, KsG, VtG, ATTNb);
  // out = attn @ Wp + bp (4096 x 2048 x 2048), dtype per detected flag
  gemm_bt<<<dim3(16, 32), 256, 0, stream>>>(ATTNb, WpT, biasB + 2304, d_out, 4096, 2048, 2048, flag, 1);
}

// Round 3
// 407.323 us; speedup vs baseline: 5.2573x; 1.1131x over previous
//
#include <hip/hip_runtime.h>

#define DEVI __device__ __forceinline__

typedef unsigned int u32;
typedef unsigned short u16;

constexpr int Bc = 2, Sc = 2048, HIDc = 2048, Hc = 16, Dc = 128;
constexpr int Mrows = Bc * Sc;                 // 4096
constexpr float SCALE = 0.08838834764831845f;  // 1/sqrt(128)

typedef float f32x4 __attribute__((ext_vector_type(4)));
typedef __bf16 bf16x8 __attribute__((ext_vector_type(8)));

DEVI float bf2f(u16 v) { return __builtin_bit_cast(float, (u32)v << 16); }
DEVI float blo(u32 u) { return __builtin_bit_cast(float, u << 16); }
DEVI float bhi(u32 u) { return __builtin_bit_cast(float, u & 0xffff0000u); }
DEVI u16 f2bf(float x) {
  u32 u = __builtin_bit_cast(u32, x);
  u32 r = (u + 0x7fffu + ((u >> 16) & 1u)) >> 16;
  return (u16)r;
}

DEVI void async16(void* lds, const void* g) {
  __builtin_amdgcn_global_load_lds((const __attribute__((address_space(1))) void*)g,
                                   (__attribute__((address_space(3))) void*)lds,
                                   16, 0, 0);
}

// ---------------- dtype detect: flag=1 if inputs are bf16-packed ----------------
__global__ void detect_dtype(const u32* __restrict__ hs, int* __restrict__ flag) {
  __shared__ int cnt;
  if (threadIdx.x == 0) cnt = 0;
  __syncthreads();
  int ok = 0;
  for (int i = threadIdx.x; i < 512; i += 256) {
    u32 lo = hs[i] & 0xffffu;
    u32 e = (lo >> 7) & 0xffu;
    if (lo == 0u || (e >= 118u && e <= 134u)) ok++;
  }
  atomicAdd(&cnt, ok);
  __syncthreads();
  if (threadIdx.x == 0) *flag = (cnt > 256) ? 1 : 0;
}

// ---------------- hidden_states -> bf16 canonical buffer ----------------
__global__ __launch_bounds__(256) void ingest_hs(const void* __restrict__ in, u16* __restrict__ out,
                                                 const int* __restrict__ flag, int n) {
  int i = (blockIdx.x * 256 + threadIdx.x) * 8;
  if (i >= n) return;
  if (*flag) {
    *(uint4*)&out[i] = *(const uint4*)&((const u16*)in)[i];
  } else {
    const float* f = (const float*)in;
    u16 tmp[8];
#pragma unroll
    for (int j = 0; j < 8; ++j) tmp[j] = f2bf(f[i + j]);
    *(uint4*)&out[i] = *(const uint4*)tmp;
  }
}

// ---------------- weight transpose (R x C) -> bf16 (C x R) ----------------
__global__ __launch_bounds__(256) void transpose_w(const void* __restrict__ in, u16* __restrict__ out,
                                                   int R, int C, const int* __restrict__ flag) {
  __shared__ u16 tile[32][33];
  const bool bf = (*flag != 0);
  int c0 = blockIdx.x * 32, r0 = blockIdx.y * 32;
  int tx = threadIdx.x & 31, ty = threadIdx.x >> 5;  // ty 0..7
#pragma unroll
  for (int i = 0; i < 32; i += 8) {
    size_t idx = (size_t)(r0 + ty + i) * C + (c0 + tx);
    tile[ty + i][tx] = bf ? ((const u16*)in)[idx] : f2bf(((const float*)in)[idx]);
  }
  __syncthreads();
#pragma unroll
  for (int i = 0; i < 32; i += 8)
    out[(size_t)(c0 + ty + i) * R + (r0 + tx)] = tile[tx][ty + i];
}

// ---------------- biases -> bf16 (bq @0, bkv @2048, bp @2304) ----------------
__global__ __launch_bounds__(256) void cvt_bias(const void* __restrict__ bq, const void* __restrict__ bkv,
                                                const void* __restrict__ bp, u16* __restrict__ out,
                                                const int* __restrict__ flag) {
  int i = blockIdx.x * 256 + threadIdx.x;
  if (i >= 4352) return;
  const bool bf = (*flag != 0);
  const void* src;
  int j;
  if (i < 2048) { src = bq; j = i; }
  else if (i < 2304) { src = bkv; j = i - 2048; }
  else { src = bp; j = i - 2304; }
  out[i] = bf ? ((const u16*)src)[j] : f2bf(((const float*)src)[j]);
}

// ---------------- bf16 GEMM: C[M,N] = A[M,K] * BT[N,K]^T + bias ----------------
// mode 0: bf16 out (row-major, stride N). mode 1: final output, dtype per *flag.
// mode 3: fused Q+KV: cols<2048 -> Qb row-major (stride 2048); col 2048..2175 ->
//         KsG chunk-swizzled; col 2176..2303 -> VtG transposed+swizzled.
__global__ __launch_bounds__(256) void gemm_bt(const u16* __restrict__ A,
                                               const u16* __restrict__ BT,
                                               const u16* __restrict__ bias,
                                               void* __restrict__ C,
                                               int M, int N, int K,
                                               const int* __restrict__ flag,
                                               int mode) {
  __shared__ __align__(16) u16 As[128 * 32];
  __shared__ __align__(16) u16 Bs[128 * 32];
  const int tid = threadIdx.x;
  const int bn = blockIdx.x, bm = blockIdx.y;
  const int wave = tid >> 6, lane = tid & 63;
  const int wm = (wave >> 1) * 64, wn = (wave & 1) * 64;
  const int lr = lane & 15, kq = lane >> 4;
  f32x4 acc[4][4] = {};
  const size_t a_base = (size_t)bm * 128 * K;
  const size_t b_base = (size_t)bn * 128 * K;
  for (int k0 = 0; k0 < K; k0 += 32) {
#pragma unroll
    for (int it = 0; it < 2; ++it) {
      int off = it * 4096 + tid * 16;  // byte offset within 8KB tile
      int row = off >> 6;              // 64 bytes per row (32 bf16)
      int col = (off & 63) >> 1;       // element col within BK
      async16(&As[off >> 1], A + a_base + (size_t)row * K + k0 + col);
      async16(&Bs[off >> 1], BT + b_base + (size_t)row * K + k0 + col);
    }
    __syncthreads();
    bf16x8 af[4], bfr[4];
#pragma unroll
    for (int i = 0; i < 4; ++i) {
      af[i]  = *(const bf16x8*)&As[(wm + i * 16 + lr) * 32 + kq * 8];
      bfr[i] = *(const bf16x8*)&Bs[(wn + i * 16 + lr) * 32 + kq * 8];
    }
#pragma unroll
    for (int mi = 0; mi < 4; ++mi)
#pragma unroll
      for (int ni = 0; ni < 4; ++ni)
        acc[mi][ni] = __builtin_amdgcn_mfma_f32_16x16x32_bf16(af[mi], bfr[ni], acc[mi][ni], 0, 0, 0);
    __syncthreads();
  }
  if (mode == 3) {
    u16* Qout = (u16*)C;
    u16* KsG = Qout + (size_t)4096 * 2048;
    u16* VtG = KsG + (size_t)4096 * 128;
    const bool isQ = (bn < 16);  // block-uniform
#pragma unroll
    for (int mi = 0; mi < 4; ++mi)
#pragma unroll
      for (int ni = 0; ni < 4; ++ni) {
        int col = bn * 128 + wn + ni * 16 + lr;
        float bv = bf2f(bias[col]);
#pragma unroll
        for (int rr = 0; rr < 4; ++rr) {
          int row = bm * 128 + wm + mi * 16 + kq * 4 + rr;
          u16 v = f2bf(acc[mi][ni][rr] + bv);
          if (isQ) {
            Qout[(size_t)row * 2048 + col] = v;
          } else {
            int c2 = col - 2048;
            if (c2 < 128) {
              int d = c2;
              KsG[(size_t)row * 128 + (((d >> 3) ^ (row & 15)) << 3) + (d & 7)] = v;
            } else {
              int d = c2 - 128, bb = row >> 11, s = row & 2047;
              VtG[((size_t)(bb * 128 + d)) * 2048 + (s & ~63) +
                  ((((s >> 3) & 7) ^ (d & 7)) << 3) + (s & 7)] = v;
            }
          }
        }
      }
    return;
  }
  const bool out16 = (mode == 0) || (*flag != 0);
#pragma unroll
  for (int mi = 0; mi < 4; ++mi)
#pragma unroll
    for (int ni = 0; ni < 4; ++ni) {
      int col = bn * 128 + wn + ni * 16 + lr;
      float bv = bf2f(bias[col]);
#pragma unroll
      for (int rr = 0; rr < 4; ++rr) {
        int row = bm * 128 + wm + mi * 16 + kq * 4 + rr;
        float v = acc[mi][ni][rr] + bv;
        size_t idx = (size_t)row * N + col;
        if (out16) ((u16*)C)[idx] = f2bf(v);
        else ((float*)C)[idx] = v;
      }
    }
}

// ---------------- causal MQA flash attention, MFMA + dbuf pipeline ----------------
// Q: (B*S, H*D) bf16. KsG: (B*S, 128) chunk-swizzled. VtG: (B, 128, S)
// chunk-swizzled per 64-key tile. O: (B*S, H*D) bf16.
// Block = (q-pair, h, b); pairs q-tiles (i, 31-i) for constant causal work.
// KV staging is double-buffered: stage(k+1) issued before compute(k); the only
// per-step sync is a raw s_waitcnt vmcnt(0) + s_barrier (no compiler drain).
constexpr int PS_STRIDE = 72;

__global__ __launch_bounds__(256) void flash_mfma(const u16* __restrict__ Q,
                                                  const u16* __restrict__ KsG,
                                                  const u16* __restrict__ VtG,
                                                  u16* __restrict__ O) {
  __shared__ __align__(16) u16 Ks[2][64 * 128];     // 2 x 16 KB, swizzled
  __shared__ __align__(16) u16 Vt[2][128 * 64];     // 2 x 16 KB, swizzled
  __shared__ __align__(16) u16 Ps[64 * PS_STRIDE];  // 9 KB, padded
  const int pairidx = blockIdx.x, h = blockIdx.y, b = blockIdx.z;
  const int tid = threadIdx.x;
  const int wave = tid >> 6, lane = tid & 63;
  const int lr = lane & 15, kq = lane >> 4;

  for (int half = 0; half < 2; ++half) {
    const int qt = (half == 0) ? pairidx : 31 - pairidx;
    // Q fragments for this wave's 16 rows, held for the whole tile
    bf16x8 qf[4];
    const u16* qbase = Q + ((size_t)(b * 2048 + qt * 64 + wave * 16 + lr)) * 2048 + h * 128;
#pragma unroll
    for (int kk = 0; kk < 4; ++kk)
      qf[kk] = *(const bf16x8*)(qbase + kk * 32 + kq * 8);
    f32x4 of[8] = {};
    float mrow[4], lrow[4];
#pragma unroll
    for (int r = 0; r < 4; ++r) { mrow[r] = -1e30f; lrow[r] = 0.f; }
    const int srow = qt * 64 + wave * 16 + kq * 4;  // + r for reg r
    const int kmax = qt * 64;

    // prologue: stage tile 0 into buffer 0
    {
      const u16* g = KsG + ((size_t)(b * 2048)) * 128;
#pragma unroll
      for (int it = 0; it < 4; ++it)
        async16(&Ks[0][it * 2048 + tid * 8], g + it * 2048 + tid * 8);
      const size_t vbase = ((size_t)b * 128) * 2048;
#pragma unroll
      for (int it = 0; it < 4; ++it) {
        int chunk = it * 256 + tid;
        async16(&Vt[0][chunk * 8], VtG + vbase + (size_t)(chunk >> 3) * 2048 + (chunk & 7) * 8);
      }
    }

    for (int k0 = 0; k0 <= kmax; k0 += 64) {
      const int cur = (k0 >> 6) & 1;
      // wait for this wave's buf[cur] staging (issued a full step ago), then sync
      asm volatile("s_waitcnt vmcnt(0)" ::: "memory");
      asm volatile("s_barrier" ::: "memory");
      // issue next tile's staging into buf[cur^1]; in flight during compute below
      if (k0 + 64 <= kmax) {
        const int nxt = cur ^ 1;
        const u16* g = KsG + ((size_t)(b * 2048 + k0 + 64)) * 128;
#pragma unroll
        for (int it = 0; it < 4; ++it)
          async16(&Ks[nxt][it * 2048 + tid * 8], g + it * 2048 + tid * 8);
        const size_t vbase = ((size_t)b * 128) * 2048 + k0 + 64;
#pragma unroll
        for (int it = 0; it < 4; ++it) {
          int chunk = it * 256 + tid;
          async16(&Vt[nxt][chunk * 8], VtG + vbase + (size_t)(chunk >> 3) * 2048 + (chunk & 7) * 8);
        }
      }

      const bool diag = (k0 == kmax);
      // ---- S = Q K^T  (16 mfma) ----
      f32x4 sf[4] = {};
#pragma unroll
      for (int nt = 0; nt < 4; ++nt) {
        int keyl = nt * 16 + lr;
#pragma unroll
        for (int kk = 0; kk < 4; ++kk) {
          const bf16x8 kf = *(const bf16x8*)&Ks[cur][keyl * 128 + ((((kk << 2) + kq) ^ lr) << 3)];
          sf[nt] = __builtin_amdgcn_mfma_f32_16x16x32_bf16(qf[kk], kf, sf[nt], 0, 0, 0);
        }
      }
      // ---- scale + causal mask ----
      float sv[4][4];
#pragma unroll
      for (int nt = 0; nt < 4; ++nt) {
        int t = k0 + nt * 16 + lr;
#pragma unroll
        for (int r = 0; r < 4; ++r) {
          float v = sf[nt][r] * SCALE;
          if (diag && t > srow + r) v = -1e30f;
          sv[nt][r] = v;
        }
      }
      // ---- online softmax (rows live across 16 lanes of a quad) ----
#pragma unroll
      for (int r = 0; r < 4; ++r) {
        float mx = fmaxf(fmaxf(sv[0][r], sv[1][r]), fmaxf(sv[2][r], sv[3][r]));
        mx = fmaxf(mx, __shfl_xor(mx, 1));
        mx = fmaxf(mx, __shfl_xor(mx, 2));
        mx = fmaxf(mx, __shfl_xor(mx, 4));
        mx = fmaxf(mx, __shfl_xor(mx, 8));
        float mnew = fmaxf(mrow[r], mx);
        float corr = __expf(mrow[r] - mnew);
        mrow[r] = mnew;
        lrow[r] *= corr;
#pragma unroll
        for (int dt = 0; dt < 8; ++dt) of[dt][r] *= corr;
        float rs = 0.f;
#pragma unroll
        for (int nt = 0; nt < 4; ++nt) {
          float p = __expf(sv[nt][r] - mnew);
          sv[nt][r] = p;
          rs += p;
        }
        rs += __shfl_xor(rs, 1);
        rs += __shfl_xor(rs, 2);
        rs += __shfl_xor(rs, 4);
        rs += __shfl_xor(rs, 8);
        lrow[r] += rs;
      }
      // ---- P: C-layout regs -> LDS (A-layout relayout) ----
#pragma unroll
      for (int nt = 0; nt < 4; ++nt)
#pragma unroll
        for (int r = 0; r < 4; ++r)
          Ps[(wave * 16 + kq * 4 + r) * PS_STRIDE + nt * 16 + lr] = f2bf(sv[nt][r]);
      // same-wave LDS RAW: DS ops in order per wave; compiler inserts lgkmcnt
      // ---- O += P V  (16 mfma) ----
#pragma unroll
      for (int ks = 0; ks < 2; ++ks) {
        const bf16x8 pf = *(const bf16x8*)&Ps[(wave * 16 + lr) * PS_STRIDE + ks * 32 + kq * 8];
#pragma unroll
        for (int dt = 0; dt < 8; ++dt) {
          int d = dt * 16 + lr;
          const bf16x8 vf = *(const bf16x8*)&Vt[cur][d * 64 + ((((ks << 2) + kq) ^ (d & 7)) << 3)];
          of[dt] = __builtin_amdgcn_mfma_f32_16x16x32_bf16(pf, vf, of[dt], 0, 0, 0);
        }
      }
    }
    // ---- epilogue: normalize + store ----
#pragma unroll
    for (int r = 0; r < 4; ++r) lrow[r] = 1.f / lrow[r];
    u16* obase = O + ((size_t)(b * 2048 + qt * 64 + wave * 16 + kq * 4)) * 2048 + h * 128;
#pragma unroll
    for (int dt = 0; dt < 8; ++dt)
#pragma unroll
      for (int r = 0; r < 4; ++r)
        obase[(size_t)r * 2048 + dt * 16 + lr] = f2bf(of[dt][r] * lrow[r]);
    __syncthreads();  // all waves done with LDS before next half restages buf 0
  }
}

extern "C" void kernel_launch(void* const* d_in, const int* in_sizes, int n_in,
                              void* d_out, int out_size, void* d_ws, size_t ws_size,
                              hipStream_t stream) {
  (void)in_sizes; (void)n_in; (void)out_size; (void)ws_size;
  const void* hs  = d_in[0];
  // d_in[1] = attention_mask: exactly causal by construction -> applied analytically
  const void* Wq  = d_in[2];
  const void* bq  = d_in[3];
  const void* Wkv = d_in[4];
  const void* bkv = d_in[5];
  const void* Wp  = d_in[6];
  const void* bp  = d_in[7];

  char* ws = (char*)d_ws;
  int* flag  = (int*)(ws + 0);
  u16* HSb   = (u16*)(ws + 256);        // 4096x2048 bf16
  u16* WqT   = (u16*)(ws + 16777472);   // 2048x2048 (contiguous with WkvT below)
  u16* WkvT  = (u16*)(ws + 25166080);   // 256x2048
  u16* WpT   = (u16*)(ws + 26214656);   // 2048x2048
  u16* biasB = (u16*)(ws + 34603264);   // 4352 (bq | bkv | bp)
  u16* Qb    = (u16*)(ws + 34611968);   // 4096x2048 (contiguous with KsG/VtG below)
  u16* KsG   = (u16*)(ws + 51389184);   // 4096x128 swizzled K
  u16* VtG   = (u16*)(ws + 52437760);   // 2x128x2048 swizzled V^T
  u16* ATTNb = (u16*)(ws + 53486336);   // 4096x2048

  detect_dtype<<<1, 256, 0, stream>>>((const u32*)hs, flag);
  ingest_hs<<<4096, 256, 0, stream>>>(hs, HSb, flag, Mrows * HIDc);
  transpose_w<<<dim3(64, 64), 256, 0, stream>>>(Wq, WqT, 2048, 2048, flag);
  transpose_w<<<dim3(8, 64), 256, 0, stream>>>(Wkv, WkvT, 2048, 256, flag);
  transpose_w<<<dim3(64, 64), 256, 0, stream>>>(Wp, WpT, 2048, 2048, flag);
  cvt_bias<<<17, 256, 0, stream>>>(bq, bkv, bp, biasB, flag);

  // fused [q | kv] = hs @ [Wq | Wkv] + [bq | bkv]  (4096 x 2304 x 2048)
  // cols<2048 -> Qb; cols>=2048 -> swizzled KsG/VtG (KsG = Qb + 4096*2048)
  gemm_bt<<<dim3(18, 32), 256, 0, stream>>>(HSb, WqT, biasB, Qb, 4096, 2304, 2048, flag, 3);
  // causal MQA attention (MFMA flash, dbuf pipeline)
  flash_mfma<<<dim3(16, 16, 2), 256, 0, stream>>>(Qb, KsG, VtG, ATTNb);
  // out = attn @ Wp + bp (4096 x 2048 x 2048), dtype per detected flag
  gemm_bt<<<dim3(16, 32), 256, 0, stream>>>(ATTNb, WpT, biasB + 2304, d_out, 4096, 2048, 2048, flag, 1);
}

// Round 4
// 363.967 us; speedup vs baseline: 5.8836x; 1.1191x over previous
//
#include <hip/hip_runtime.h>

#define DEVI __device__ __forceinline__

typedef unsigned int u32;
typedef unsigned short u16;

constexpr int Bc = 2, Sc = 2048, HIDc = 2048, Hc = 16, Dc = 128;
constexpr int Mrows = Bc * Sc;                 // 4096
constexpr float SCALE = 0.08838834764831845f;  // 1/sqrt(128)

typedef float f32x4 __attribute__((ext_vector_type(4)));
typedef __bf16 bf16x8 __attribute__((ext_vector_type(8)));

DEVI float bf2f(u16 v) { return __builtin_bit_cast(float, (u32)v << 16); }
DEVI u16 f2bf(float x) {
  u32 u = __builtin_bit_cast(u32, x);
  u32 r = (u + 0x7fffu + ((u >> 16) & 1u)) >> 16;
  return (u16)r;
}

DEVI void async16(void* lds, const void* g) {
  __builtin_amdgcn_global_load_lds((const __attribute__((address_space(1))) void*)g,
                                   (__attribute__((address_space(3))) void*)lds,
                                   16, 0, 0);
}

// ---------------- dtype detect: flag=1 if inputs are bf16-packed ----------------
__global__ void detect_dtype(const u32* __restrict__ hs, int* __restrict__ flag) {
  __shared__ int cnt;
  if (threadIdx.x == 0) cnt = 0;
  __syncthreads();
  int ok = 0;
  for (int i = threadIdx.x; i < 512; i += 256) {
    u32 lo = hs[i] & 0xffffu;
    u32 e = (lo >> 7) & 0xffu;
    if (lo == 0u || (e >= 118u && e <= 134u)) ok++;
  }
  atomicAdd(&cnt, ok);
  __syncthreads();
  if (threadIdx.x == 0) *flag = (cnt > 256) ? 1 : 0;
}

// ---------------- hidden_states -> bf16 canonical buffer ----------------
__global__ __launch_bounds__(256) void ingest_hs(const void* __restrict__ in, u16* __restrict__ out,
                                                 const int* __restrict__ flag, int n) {
  int i = (blockIdx.x * 256 + threadIdx.x) * 8;
  if (i >= n) return;
  if (*flag) {
    *(uint4*)&out[i] = *(const uint4*)&((const u16*)in)[i];
  } else {
    const float* f = (const float*)in;
    u16 tmp[8];
#pragma unroll
    for (int j = 0; j < 8; ++j) tmp[j] = f2bf(f[i + j]);
    *(uint4*)&out[i] = *(const uint4*)tmp;
  }
}

// ---------------- weight transpose (R x C) -> bf16 (C x R) ----------------
__global__ __launch_bounds__(256) void transpose_w(const void* __restrict__ in, u16* __restrict__ out,
                                                   int R, int C, const int* __restrict__ flag) {
  __shared__ u16 tile[32][33];
  const bool bf = (*flag != 0);
  int c0 = blockIdx.x * 32, r0 = blockIdx.y * 32;
  int tx = threadIdx.x & 31, ty = threadIdx.x >> 5;  // ty 0..7
#pragma unroll
  for (int i = 0; i < 32; i += 8) {
    size_t idx = (size_t)(r0 + ty + i) * C + (c0 + tx);
    tile[ty + i][tx] = bf ? ((const u16*)in)[idx] : f2bf(((const float*)in)[idx]);
  }
  __syncthreads();
#pragma unroll
  for (int i = 0; i < 32; i += 8)
    out[(size_t)(c0 + ty + i) * R + (r0 + tx)] = tile[tx][ty + i];
}

// ---------------- biases -> bf16 (bq @0, bkv @2048, bp @2304) ----------------
__global__ __launch_bounds__(256) void cvt_bias(const void* __restrict__ bq, const void* __restrict__ bkv,
                                                const void* __restrict__ bp, u16* __restrict__ out,
                                                const int* __restrict__ flag) {
  int i = blockIdx.x * 256 + threadIdx.x;
  if (i >= 4352) return;
  const bool bf = (*flag != 0);
  const void* src;
  int j;
  if (i < 2048) { src = bq; j = i; }
  else if (i < 2304) { src = bkv; j = i - 2048; }
  else { src = bp; j = i - 2304; }
  out[i] = bf ? ((const u16*)src)[j] : f2bf(((const float*)src)[j]);
}

// ---------------- bf16 GEMM: C[M,N] = A[M,K] * BT[N,K]^T + bias ----------------
// Pipelined: BK=64, double-buffered LDS, one raw vmcnt(0)+s_barrier per step;
// staging for step s+1 is in flight across step s's compute.
// LDS layout: 16B chunk slot c of row r holds global k-chunk (c ^ (r&7)) ->
// fragment ds_read_b128 hits every bank exactly 8 dwords (conflict-free).
// mode 0: bf16 out (row-major, stride N). mode 1: final output, dtype per *flag.
// mode 3: fused Q+KV: cols<2048 -> Qb row-major; 2048..2175 -> KsG swizzled;
//         2176..2303 -> VtG transposed+swizzled.
__global__ __launch_bounds__(256) void gemm_bt(const u16* __restrict__ A,
                                               const u16* __restrict__ BT,
                                               const u16* __restrict__ bias,
                                               void* __restrict__ C,
                                               int M, int N, int K,
                                               const int* __restrict__ flag,
                                               int mode) {
  __shared__ __align__(16) u16 As[2][128 * 64];  // 2 x 16 KB
  __shared__ __align__(16) u16 Bs[2][128 * 64];  // 2 x 16 KB
  const int tid = threadIdx.x;
  const int bn = blockIdx.x, bm = blockIdx.y;
  const int wave = tid >> 6, lane = tid & 63;
  const int wm = (wave >> 1) * 64, wn = (wave & 1) * 64;
  const int lr = lane & 15, kq = lane >> 4;
  f32x4 acc[4][4] = {};
  const size_t a_base = (size_t)bm * 128 * K;
  const size_t b_base = (size_t)bn * 128 * K;

  // stage one 128x64 tile pair into buffer buf, fetch-permuted for XOR swizzle
#define STAGE(k0, buf)                                                             \
  {                                                                                \
    _Pragma("unroll") for (int it = 0; it < 4; ++it) {                             \
      int l = it * 256 + tid;                                                      \
      int r = l >> 3, c = l & 7;                                                   \
      int gc = (c ^ (r & 7)) << 3;                                                 \
      async16(&As[buf][l * 8], A + a_base + (size_t)r * K + (k0) + gc);            \
      async16(&Bs[buf][l * 8], BT + b_base + (size_t)r * K + (k0) + gc);           \
    }                                                                              \
  }

  STAGE(0, 0);
  const int nsteps = K >> 6;
  for (int s = 0; s < nsteps; ++s) {
    const int cur = s & 1;
    asm volatile("s_waitcnt vmcnt(0)" ::: "memory");
    asm volatile("s_barrier" ::: "memory");
    if (s + 1 < nsteps) STAGE((s + 1) << 6, cur ^ 1);
#pragma unroll
    for (int ks = 0; ks < 2; ++ks) {
      bf16x8 af[4], bfr[4];
#pragma unroll
      for (int i = 0; i < 4; ++i) {
        int ra = wm + i * 16 + lr;
        af[i]  = *(const bf16x8*)&As[cur][ra * 64 + (((ks * 4 + kq) ^ (ra & 7)) << 3)];
        int rb = wn + i * 16 + lr;
        bfr[i] = *(const bf16x8*)&Bs[cur][rb * 64 + (((ks * 4 + kq) ^ (rb & 7)) << 3)];
      }
#pragma unroll
      for (int mi = 0; mi < 4; ++mi)
#pragma unroll
        for (int ni = 0; ni < 4; ++ni)
          acc[mi][ni] = __builtin_amdgcn_mfma_f32_16x16x32_bf16(af[mi], bfr[ni], acc[mi][ni], 0, 0, 0);
    }
  }
#undef STAGE

  if (mode == 3) {
    u16* Qout = (u16*)C;
    u16* KsG = Qout + (size_t)4096 * 2048;
    u16* VtG = KsG + (size_t)4096 * 128;
    const bool isQ = (bn < 16);  // block-uniform
#pragma unroll
    for (int mi = 0; mi < 4; ++mi)
#pragma unroll
      for (int ni = 0; ni < 4; ++ni) {
        int col = bn * 128 + wn + ni * 16 + lr;
        float bv = bf2f(bias[col]);
#pragma unroll
        for (int rr = 0; rr < 4; ++rr) {
          int row = bm * 128 + wm + mi * 16 + kq * 4 + rr;
          u16 v = f2bf(acc[mi][ni][rr] + bv);
          if (isQ) {
            Qout[(size_t)row * 2048 + col] = v;
          } else {
            int c2 = col - 2048;
            if (c2 < 128) {
              int d = c2;
              KsG[(size_t)row * 128 + (((d >> 3) ^ (row & 15)) << 3) + (d & 7)] = v;
            } else {
              int d = c2 - 128, bb = row >> 11, s = row & 2047;
              VtG[((size_t)(bb * 128 + d)) * 2048 + (s & ~63) +
                  ((((s >> 3) & 7) ^ (d & 7)) << 3) + (s & 7)] = v;
            }
          }
        }
      }
    return;
  }
  const bool out16 = (mode == 0) || (*flag != 0);
#pragma unroll
  for (int mi = 0; mi < 4; ++mi)
#pragma unroll
    for (int ni = 0; ni < 4; ++ni) {
      int col = bn * 128 + wn + ni * 16 + lr;
      float bv = bf2f(bias[col]);
#pragma unroll
      for (int rr = 0; rr < 4; ++rr) {
        int row = bm * 128 + wm + mi * 16 + kq * 4 + rr;
        float v = acc[mi][ni][rr] + bv;
        size_t idx = (size_t)row * N + col;
        if (out16) ((u16*)C)[idx] = f2bf(v);
        else ((float*)C)[idx] = v;
      }
    }
}

// ---------------- causal MQA flash attention, MFMA + dbuf pipeline ----------------
constexpr int PS_STRIDE = 72;

__global__ __launch_bounds__(256) void flash_mfma(const u16* __restrict__ Q,
                                                  const u16* __restrict__ KsG,
                                                  const u16* __restrict__ VtG,
                                                  u16* __restrict__ O) {
  __shared__ __align__(16) u16 Ks[2][64 * 128];     // 2 x 16 KB, swizzled
  __shared__ __align__(16) u16 Vt[2][128 * 64];     // 2 x 16 KB, swizzled
  __shared__ __align__(16) u16 Ps[64 * PS_STRIDE];  // 9 KB, padded
  const int pairidx = blockIdx.x, h = blockIdx.y, b = blockIdx.z;
  const int tid = threadIdx.x;
  const int wave = tid >> 6, lane = tid & 63;
  const int lr = lane & 15, kq = lane >> 4;

  for (int half = 0; half < 2; ++half) {
    const int qt = (half == 0) ? pairidx : 31 - pairidx;
    bf16x8 qf[4];
    const u16* qbase = Q + ((size_t)(b * 2048 + qt * 64 + wave * 16 + lr)) * 2048 + h * 128;
#pragma unroll
    for (int kk = 0; kk < 4; ++kk)
      qf[kk] = *(const bf16x8*)(qbase + kk * 32 + kq * 8);
    f32x4 of[8] = {};
    float mrow[4], lrow[4];
#pragma unroll
    for (int r = 0; r < 4; ++r) { mrow[r] = -1e30f; lrow[r] = 0.f; }
    const int srow = qt * 64 + wave * 16 + kq * 4;  // + r for reg r
    const int kmax = qt * 64;

    {  // prologue: stage tile 0 into buffer 0
      const u16* g = KsG + ((size_t)(b * 2048)) * 128;
#pragma unroll
      for (int it = 0; it < 4; ++it)
        async16(&Ks[0][it * 2048 + tid * 8], g + it * 2048 + tid * 8);
      const size_t vbase = ((size_t)b * 128) * 2048;
#pragma unroll
      for (int it = 0; it < 4; ++it) {
        int chunk = it * 256 + tid;
        async16(&Vt[0][chunk * 8], VtG + vbase + (size_t)(chunk >> 3) * 2048 + (chunk & 7) * 8);
      }
    }

    for (int k0 = 0; k0 <= kmax; k0 += 64) {
      const int cur = (k0 >> 6) & 1;
      asm volatile("s_waitcnt vmcnt(0)" ::: "memory");
      asm volatile("s_barrier" ::: "memory");
      if (k0 + 64 <= kmax) {
        const int nxt = cur ^ 1;
        const u16* g = KsG + ((size_t)(b * 2048 + k0 + 64)) * 128;
#pragma unroll
        for (int it = 0; it < 4; ++it)
          async16(&Ks[nxt][it * 2048 + tid * 8], g + it * 2048 + tid * 8);
        const size_t vbase = ((size_t)b * 128) * 2048 + k0 + 64;
#pragma unroll
        for (int it = 0; it < 4; ++it) {
          int chunk = it * 256 + tid;
          async16(&Vt[nxt][chunk * 8], VtG + vbase + (size_t)(chunk >> 3) * 2048 + (chunk & 7) * 8);
        }
      }

      const bool diag = (k0 == kmax);
      // ---- S = Q K^T  (16 mfma) ----
      f32x4 sf[4] = {};
#pragma unroll
      for (int nt = 0; nt < 4; ++nt) {
        int keyl = nt * 16 + lr;
#pragma unroll
        for (int kk = 0; kk < 4; ++kk) {
          const bf16x8 kf = *(const bf16x8*)&Ks[cur][keyl * 128 + ((((kk << 2) + kq) ^ lr) << 3)];
          sf[nt] = __builtin_amdgcn_mfma_f32_16x16x32_bf16(qf[kk], kf, sf[nt], 0, 0, 0);
        }
      }
      // ---- scale + causal mask ----
      float sv[4][4];
#pragma unroll
      for (int nt = 0; nt < 4; ++nt) {
        int t = k0 + nt * 16 + lr;
#pragma unroll
        for (int r = 0; r < 4; ++r) {
          float v = sf[nt][r] * SCALE;
          if (diag && t > srow + r) v = -1e30f;
          sv[nt][r] = v;
        }
      }
      // ---- online softmax (rows live across 16 lanes of a quad) ----
#pragma unroll
      for (int r = 0; r < 4; ++r) {
        float mx = fmaxf(fmaxf(sv[0][r], sv[1][r]), fmaxf(sv[2][r], sv[3][r]));
        mx = fmaxf(mx, __shfl_xor(mx, 1));
        mx = fmaxf(mx, __shfl_xor(mx, 2));
        mx = fmaxf(mx, __shfl_xor(mx, 4));
        mx = fmaxf(mx, __shfl_xor(mx, 8));
        float mnew = fmaxf(mrow[r], mx);
        float corr = __expf(mrow[r] - mnew);
        mrow[r] = mnew;
        lrow[r] *= corr;
#pragma unroll
        for (int dt = 0; dt < 8; ++dt) of[dt][r] *= corr;
        float rs = 0.f;
#pragma unroll
        for (int nt = 0; nt < 4; ++nt) {
          float p = __expf(sv[nt][r] - mnew);
          sv[nt][r] = p;
          rs += p;
        }
        rs += __shfl_xor(rs, 1);
        rs += __shfl_xor(rs, 2);
        rs += __shfl_xor(rs, 4);
        rs += __shfl_xor(rs, 8);
        lrow[r] += rs;
      }
      // ---- P: C-layout regs -> LDS (A-layout relayout) ----
#pragma unroll
      for (int nt = 0; nt < 4; ++nt)
#pragma unroll
        for (int r = 0; r < 4; ++r)
          Ps[(wave * 16 + kq * 4 + r) * PS_STRIDE + nt * 16 + lr] = f2bf(sv[nt][r]);
      // ---- O += P V  (16 mfma) ----
#pragma unroll
      for (int ks = 0; ks < 2; ++ks) {
        const bf16x8 pf = *(const bf16x8*)&Ps[(wave * 16 + lr) * PS_STRIDE + ks * 32 + kq * 8];
#pragma unroll
        for (int dt = 0; dt < 8; ++dt) {
          int d = dt * 16 + lr;
          const bf16x8 vf = *(const bf16x8*)&Vt[cur][d * 64 + ((((ks << 2) + kq) ^ (d & 7)) << 3)];
          of[dt] = __builtin_amdgcn_mfma_f32_16x16x32_bf16(pf, vf, of[dt], 0, 0, 0);
        }
      }
    }
    // ---- epilogue: normalize + store ----
#pragma unroll
    for (int r = 0; r < 4; ++r) lrow[r] = 1.f / lrow[r];
    u16* obase = O + ((size_t)(b * 2048 + qt * 64 + wave * 16 + kq * 4)) * 2048 + h * 128;
#pragma unroll
    for (int dt = 0; dt < 8; ++dt)
#pragma unroll
      for (int r = 0; r < 4; ++r)
        obase[(size_t)r * 2048 + dt * 16 + lr] = f2bf(of[dt][r] * lrow[r]);
    __syncthreads();  // all waves done with LDS before next half restages buf 0
  }
}

extern "C" void kernel_launch(void* const* d_in, const int* in_sizes, int n_in,
                              void* d_out, int out_size, void* d_ws, size_t ws_size,
                              hipStream_t stream) {
  (void)in_sizes; (void)n_in; (void)out_size; (void)ws_size;
  const void* hs  = d_in[0];
  // d_in[1] = attention_mask: exactly causal by construction -> applied analytically
  const void* Wq  = d_in[2];
  const void* bq  = d_in[3];
  const void* Wkv = d_in[4];
  const void* bkv = d_in[5];
  const void* Wp  = d_in[6];
  const void* bp  = d_in[7];

  char* ws = (char*)d_ws;
  int* flag  = (int*)(ws + 0);
  u16* HSb   = (u16*)(ws + 256);        // 4096x2048 bf16
  u16* WqT   = (u16*)(ws + 16777472);   // 2048x2048 (contiguous with WkvT below)
  u16* WkvT  = (u16*)(ws + 25166080);   // 256x2048
  u16* WpT   = (u16*)(ws + 26214656);   // 2048x2048
  u16* biasB = (u16*)(ws + 34603264);   // 4352 (bq | bkv | bp)
  u16* Qb    = (u16*)(ws + 34611968);   // 4096x2048 (contiguous with KsG/VtG below)
  u16* KsG   = (u16*)(ws + 51389184);   // 4096x128 swizzled K
  u16* VtG   = (u16*)(ws + 52437760);   // 2x128x2048 swizzled V^T
  u16* ATTNb = (u16*)(ws + 53486336);   // 4096x2048

  detect_dtype<<<1, 256, 0, stream>>>((const u32*)hs, flag);
  ingest_hs<<<4096, 256, 0, stream>>>(hs, HSb, flag, Mrows * HIDc);
  transpose_w<<<dim3(64, 64), 256, 0, stream>>>(Wq, WqT, 2048, 2048, flag);
  transpose_w<<<dim3(8, 64), 256, 0, stream>>>(Wkv, WkvT, 2048, 256, flag);
  transpose_w<<<dim3(64, 64), 256, 0, stream>>>(Wp, WpT, 2048, 2048, flag);
  cvt_bias<<<17, 256, 0, stream>>>(bq, bkv, bp, biasB, flag);

  // fused [q | kv] = hs @ [Wq | Wkv] + [bq | bkv]  (4096 x 2304 x 2048)
  gemm_bt<<<dim3(18, 32), 256, 0, stream>>>(HSb, WqT, biasB, Qb, 4096, 2304, 2048, flag, 3);
  // causal MQA attention (MFMA flash, dbuf pipeline)
  flash_mfma<<<dim3(16, 16, 2), 256, 0, stream>>>(Qb, KsG, VtG, ATTNb);
  // out = attn @ Wp + bp (4096 x 2048 x 2048), dtype per detected flag
  gemm_bt<<<dim3(16, 32), 256, 0, stream>>>(ATTNb, WpT, biasB + 2304, d_out, 4096, 2048, 2048, flag, 1);
}